// Round 1
// 206.120 us; speedup vs baseline: 1.0104x; 1.0104x over previous
//
#include <hip/hip_runtime.h>

#define T_DIM 4096
#define B_DIM 64
#define H_DIM 128
#define Q_DIM 1024
#define K_DIM 31
#define PADC 15
#define WL 128
#define NT 512

__device__ __forceinline__ float fast_tanh(float x) {
    float xc = fminf(fmaxf(x, -15.f), 15.f);
    float e = __expf(2.f * xc);
    return (e - 1.f) * __builtin_amdgcn_rcpf(e + 1.f);
}

// One block per batch element. 512 threads. All float tensors f32.
__global__ __launch_bounds__(NT) void lsa_kernel(
    const float* __restrict__ enc,          // [T,B,H]
    const int*   __restrict__ num_tokens,   // [B]
    const float* __restrict__ query,        // [1,B,Q]
    const float* __restrict__ cum,          // [B,T]
    const float* __restrict__ init_cum,     // [B,1]
    const int*   __restrict__ window_start, // [B]
    const float* __restrict__ Wq,           // [H,Q]
    const float* __restrict__ bq,           // [H]
    const float* __restrict__ conv_w,       // [H,1,K]
    const float* __restrict__ conv_b,       // [H]
    const float* __restrict__ vvec,         // [H]
    float* __restrict__ out)                // ctx[B*H] | cum_new[B*T] | align_full[B*T] | ws_new[B]
{
    const int b   = blockIdx.x;
    const int tid = threadIdx.x;
    const int ws   = window_start[b];
    const int ntok = num_tokens[b];

    __shared__ float s_q[Q_DIM];                       // 4 KB
    __shared__ __align__(16) float s_enc[WL * H_DIM];  // 64 KB, [w][h], linear for global_load_lds
    __shared__ float s_loc[WL + 2 * PADC];             // 158 f
    __shared__ __align__(16) float s_convw[H_DIM * K_DIM]; // 15.5 KB
    __shared__ float s_qpb[H_DIM];
    __shared__ float s_v[H_DIM];
    __shared__ float s_part[4 * WL];                   // reused
    __shared__ float s_align[WL];

    // ---- stage SMALL operands only (query, conv weights, v, loc window) ----
    // enc/cum moved after barrier 2 so their latency hides under gemv+conv.
    {
        const float2* q2 = reinterpret_cast<const float2*>(query + (size_t)b * Q_DIM);
        float2 v = q2[tid];
        s_q[2 * tid] = v.x; s_q[2 * tid + 1] = v.y;
    }
    {   // conv_w: 3968 floats = 992 float4
        const float4* cw4 = reinterpret_cast<const float4*>(conv_w);
        float4* sw4 = reinterpret_cast<float4*>(s_convw);
        for (int i = tid; i < (H_DIM * K_DIM) / 4; i += NT) sw4[i] = cw4[i];
    }
    if (tid < H_DIM) s_v[tid] = vvec[tid];
    if (tid < WL + 2 * PADC) {
        int p = ws + tid;
        float val;
        if (p < PADC) val = init_cum[b];
        else {
            int t = p - PADC;
            val = (t < T_DIM && t < ntok) ? cum[(size_t)b * T_DIM + t] : 0.f;
        }
        s_loc[tid] = val;
    }
    __syncthreads();  // sync1: drains only ~20 KB of loads

    // ---- qp[h] = dot(query, Wq[h]) + bq[h] + conv_b[h]; 4 threads per h ----
    {
        int h = tid >> 2, part = tid & 3;
        const float4* wrow = reinterpret_cast<const float4*>(Wq + (size_t)h * Q_DIM + part * 256);
        const float* qs = &s_q[part * 256];
        float acc = 0.f;
        #pragma unroll 8
        for (int i = 0; i < 64; ++i) {
            float4 w4 = wrow[i];
            acc += w4.x * qs[4 * i]     + w4.y * qs[4 * i + 1]
                 + w4.z * qs[4 * i + 2] + w4.w * qs[4 * i + 3];
        }
        acc += __shfl_xor(acc, 1);
        acc += __shfl_xor(acc, 2);
        if (part == 0) s_qpb[h] = acc + bq[h] + conv_b[h];
    }
    __syncthreads();  // sync2

    // ---- issue async enc-window -> LDS (direct-to-LDS, no VGPR round trip).
    //      vmcnt drain lands at sync3, fully hidden under the conv phase. ----
    {
        int wv = tid >> 6, lane = tid & 63;
        #pragma unroll
        for (int i = 0; i < 8; ++i) {
            // chunk index ci in [0,4096): 16B chunks of the 64 KB window, linear
            int ci = (wv << 9) + (i << 6) + lane;
            int w = ci >> 5, c = ci & 31;
            const float* src = enc + ((size_t)(ws + w) * B_DIM + b) * H_DIM + (c << 2);
            // LDS dest: wave-uniform base; HW adds lane*16. Layout matches s_enc[w][h] linearly.
            __builtin_amdgcn_global_load_lds(
                (const __attribute__((address_space(1))) uint32_t*)src,
                (__attribute__((address_space(3))) uint32_t*)(
                    reinterpret_cast<char*>(s_enc) + (wv << 13) + (i << 10)),
                16, 0, 0);
        }
    }
    // ---- cum row prefetch to registers (also drains at sync3, hidden) ----
    const int p0 = tid * 8;                      // 512*8 = 4096
    const float4* cin = reinterpret_cast<const float4*>(cum + (size_t)b * T_DIM + p0);
    float4 c0 = cin[0], c1 = cin[1];

    // ---- conv(K=31) + tanh + v-weighted score, partial over h (4 groups of 32) ----
    {
        int w = tid & (WL - 1);
        int g = tid >> 7;
        float sc = 0.f;
        for (int hh = 0; hh < 32; ++hh) {
            int h = g * 32 + hh;
            float a = s_qpb[h];
            const float* cw = &s_convw[h * K_DIM];
            #pragma unroll
            for (int k = 0; k < K_DIM; ++k) a += s_loc[w + k] * cw[k];
            sc += s_v[h] * fast_tanh(a);
        }
        s_part[g * WL + w] = sc;
    }
    __syncthreads();  // sync3: drains conv stores + async enc loads + cum regs

    // ---- merged partial-combine + mask + softmax + argmax + ws_new (one wave) ----
    if (tid < 64) {
        float a0 = s_part[tid]      + s_part[WL + tid]
                 + s_part[2 * WL + tid]      + s_part[3 * WL + tid];
        float a1 = s_part[tid + 64] + s_part[WL + tid + 64]
                 + s_part[2 * WL + tid + 64] + s_part[3 * WL + tid + 64];
        if ((ws + tid)      >= ntok) a0 = -__builtin_inff();
        if ((ws + tid + 64) >= ntok) a1 = -__builtin_inff();
        float m = fmaxf(a0, a1);
        for (int off = 32; off; off >>= 1) m = fmaxf(m, __shfl_xor(m, off));
        float e0 = __expf(a0 - m), e1 = __expf(a1 - m);
        float s = e0 + e1;
        for (int off = 32; off; off >>= 1) s += __shfl_xor(s, off);
        float inv = __builtin_amdgcn_rcpf(s);
        e0 *= inv; e1 *= inv;
        s_align[tid] = e0; s_align[tid + 64] = e1;
        // argmax (first-index tie-break), exp/normalize is monotone
        float bv = e0; int bi = tid;
        if (e1 > bv) { bv = e1; bi = tid + 64; }
        for (int off = 32; off; off >>= 1) {
            float ov = __shfl_xor(bv, off);
            int   oi = __shfl_xor(bi, off);
            if (ov > bv || (ov == bv && oi < bi)) { bv = ov; bi = oi; }
        }
        if (tid == 0) {
            int wsn = ws + bi - WL / 2;
            int hi = ntok - WL;
            if (wsn > hi) wsn = hi;
            if (wsn < 0) wsn = 0;
            out[(size_t)B_DIM * H_DIM + 2 * (size_t)B_DIM * T_DIM + b] = (float)wsn;
        }
    }
    __syncthreads();  // sync4

    // ---- context[h] = sum_w align[w] * enc_w[w,h] from LDS ----
    {
        int h = tid & (H_DIM - 1);
        int g = tid >> 7;
        float acc = 0.f;
        #pragma unroll 8
        for (int wi = 0; wi < 32; ++wi) {
            int w = g * 32 + wi;
            acc += s_align[w] * s_enc[w * H_DIM + h];
        }
        s_part[g * H_DIM + h] = acc;
    }
    __syncthreads();  // sync5
    if (tid < H_DIM) {
        float c = s_part[tid] + s_part[H_DIM + tid] + s_part[2 * H_DIM + tid] + s_part[3 * H_DIM + tid];
        out[(size_t)b * H_DIM + tid] = c;
    }

    // ---- full-row writes using prefetched cum registers ----
    {
        float* out_cum   = out + (size_t)B_DIM * H_DIM;
        float* out_align = out_cum + (size_t)B_DIM * T_DIM;
        float ci[8] = {c0.x, c0.y, c0.z, c0.w, c1.x, c1.y, c1.z, c1.w};
        float oc[8], oa[8];
        #pragma unroll
        for (int i = 0; i < 8; ++i) {
            int p = p0 + i;
            float c = (p < ntok) ? ci[i] : 0.f;
            float a = ((unsigned)(p - ws) < (unsigned)WL) ? s_align[p - ws] : 0.f;
            oc[i] = c + a;
            oa[i] = a;
        }
        float4* pc = reinterpret_cast<float4*>(out_cum   + (size_t)b * T_DIM + p0);
        float4* pa = reinterpret_cast<float4*>(out_align + (size_t)b * T_DIM + p0);
        pc[0] = make_float4(oc[0], oc[1], oc[2], oc[3]);
        pc[1] = make_float4(oc[4], oc[5], oc[6], oc[7]);
        pa[0] = make_float4(oa[0], oa[1], oa[2], oa[3]);
        pa[1] = make_float4(oa[4], oa[5], oa[6], oa[7]);
    }
}

extern "C" void kernel_launch(void* const* d_in, const int* in_sizes, int n_in,
                              void* d_out, int out_size, void* d_ws, size_t ws_size,
                              hipStream_t stream) {
    const float* enc  = (const float*)d_in[0];
    // d_in[1] = tokens_mask (bool) — unused; mask derived from num_tokens
    const int* ntok   = (const int*)d_in[2];
    const float* qry  = (const float*)d_in[3];
    const float* cum  = (const float*)d_in[4];
    const float* ic   = (const float*)d_in[5];
    const int* wstart = (const int*)d_in[6];
    const float* Wq   = (const float*)d_in[7];
    const float* bq   = (const float*)d_in[8];
    const float* cw   = (const float*)d_in[9];
    const float* cb   = (const float*)d_in[10];
    const float* vv   = (const float*)d_in[11];
    float* out        = (float*)d_out;

    lsa_kernel<<<B_DIM, NT, 0, stream>>>(enc, ntok, qry, cum, ic, wstart,
                                         Wq, bq, cw, cb, vv, out);
}